// Round 4
// baseline (192.867 us; speedup 1.0000x reference)
//
#include <hip/hip_runtime.h>

#define DIM    256
#define NCODES 1024
#define BATCH  16
#define SEQ    2048
#define NROWS  (BATCH * SEQ)   // 32768
#define NTHR   256

typedef short short8 __attribute__((ext_vector_type(8)));
typedef float f32x4 __attribute__((ext_vector_type(4)));
typedef unsigned long long u64;

__device__ __forceinline__ float wave_reduce_sum(float s) {
#pragma unroll
  for (int off = 32; off > 0; off >>= 1) s += __shfl_down(s, off, 64);
  return s;
}

// round-to-nearest-even float -> bf16 (raw short)
__device__ __forceinline__ short f2bf(float f) {
  unsigned u = __builtin_bit_cast(unsigned, f);
  u = (u + 0x7fff + ((u >> 16) & 1)) >> 16;
  return (short)u;
}
__device__ __forceinline__ float bf2f(short s) {
  unsigned u = ((unsigned)(unsigned short)s) << 16;
  return __builtin_bit_cast(float, u);
}

// strictly monotone float -> u32 (total order == float order; no NaNs here)
__device__ __forceinline__ unsigned fenc(float f) {
  unsigned u = __builtin_bit_cast(unsigned, f);
  return (u & 0x80000000u) ? ~u : (u | 0x80000000u);
}

// async global -> LDS, 16B per lane. LDS dest = wave-uniform base + lane*16.
__device__ __forceinline__ void cp16(const void* g, void* l) {
  __builtin_amdgcn_global_load_lds(
      (const __attribute__((address_space(1))) unsigned*)g,
      (__attribute__((address_space(3))) unsigned*)l, 16, 0, 0);
}

// ---- fused prep: A-plane split (0..2047), B pack (2048..2111),
//      mask/denom (2112..2127), keys init (2128..2143) ----
// abuf: [(R*8+s)*1024 + ((rb16*2+reg)*4+kgl)*16 + m] short8
//   row = R*128 + rb16*16 + m ; dims = s*32 + kgl*8 + j ; reg0=hi reg1=lo
// bbuf: [(g128*8+s)*1024 + ((nb8*2+reg)*4+kgl)*16 + m] short8
//   code = g128*128 + nb8*16 + m ; dims = s*32 + kgl*8 + j
__global__ __launch_bounds__(NTHR) void k_prep(const float* __restrict__ feat,
                                               const float* __restrict__ cb,
                                               const float* __restrict__ mask,
                                               short8* __restrict__ abuf,
                                               short8* __restrict__ bbuf,
                                               float* __restrict__ cbsq,
                                               float* __restrict__ denom,
                                               float* __restrict__ lsum,
                                               u64* __restrict__ keys) {
  const int bid = blockIdx.x;
  const int t = threadIdx.x;
  __shared__ float tile[16 * 257];
  if (bid < 2048) {
    // ---- prep A: one (rowTile R, chunk s) per block ----
    const int R = bid >> 3;
    const int s = bid & 7;
    const float4* __restrict__ fsrc = (const float4*)feat;
    short8* dst = abuf + (size_t)(R * 8 + s) * 1024;
#pragma unroll
    for (int it = 0; it < 2; ++it) {
      const int p = it * NTHR + t;       // 512 items
      const int rl = p >> 2;             // row_local [0,128)
      const int kgl = p & 3;
      const int row = R * 128 + rl;
      const size_t f4 = (size_t)row * 64 + s * 8 + kgl * 2;
      const float4 x0 = fsrc[f4];
      const float4 x1 = fsrc[f4 + 1];
      const float xs[8] = {x0.x, x0.y, x0.z, x0.w, x1.x, x1.y, x1.z, x1.w};
      short8 hi, lo;
#pragma unroll
      for (int j = 0; j < 8; ++j) {
        const short hh = f2bf(xs[j]);
        hi[j] = hh;
        lo[j] = f2bf(xs[j] - bf2f(hh));
      }
      const int rb16 = rl >> 4, m = rl & 15;
      dst[((rb16 * 2 + 0) * 4 + kgl) * 16 + m] = hi;
      dst[((rb16 * 2 + 1) * 4 + kgl) * 16 + m] = lo;
    }
  } else if (bid < 2112) {
    // ---- prep B: 16 codes per block ----
    const int nb = bid - 2048;
    const float* src = cb + (size_t)nb * 16 * DIM;
#pragma unroll
    for (int i = 0; i < 16; ++i) tile[i * 257 + t] = src[i * DIM + t];
    __syncthreads();
#pragma unroll
    for (int it = 0; it < 4; ++it) {
      const int idx = it * NTHR + t;
      const int kg = idx >> 4;
      const int m = idx & 15;
      const int reg = kg >> 5;
      const int sk = kg & 31;
      const int sg = sk >> 2;
      const int kgl = sk & 3;
      short8 v;
#pragma unroll
      for (int j = 0; j < 8; ++j) {
        const float w = tile[m * 257 + sk * 8 + j];
        const short h = f2bf(w);
        v[j] = reg ? f2bf(w - bf2f(h)) : h;
      }
      bbuf[(size_t)((nb >> 3) * 8 + sg) * 1024 +
           (((nb & 7) * 2 + reg) * 4 + kgl) * 16 + m] = v;
    }
    if (t < 16) {
      float s2 = 0.f;
      for (int c = 0; c < DIM; ++c) { const float w = tile[t * 257 + c]; s2 = fmaf(w, w, s2); }
      cbsq[nb * 16 + t] = s2;
    }
  } else if (bid < 2128) {
    // ---- mask sums + zero loss accumulators ----
    const int b = bid - 2112;
    float s = 0.f;
    for (int i = t; i < SEQ; i += NTHR) s += mask[b * SEQ + i];
    s = wave_reduce_sum(s);
    __shared__ float red[NTHR / 64];
    if ((t & 63) == 0) red[t >> 6] = s;
    __syncthreads();
    if (t == 0) { denom[b] = red[0] + red[1] + red[2] + red[3]; lsum[b] = 0.f; }
  } else {
    // ---- keys init: 16 blocks x 2048 keys ----
    u64* kp = keys + (size_t)(bid - 2128) * 2048 + t;
#pragma unroll
    for (int i = 0; i < 8; ++i) kp[i * NTHR] = ~0ULL;
  }
}

// ---- MFMA score, barrier-free main loop, atomicMin argmin ----
// Block: 256 rows x 64 codes. B (64 codes, full K, hi+lo) persistent in LDS
// (64 KB), loaded once via global_load_lds + one __syncthreads. Each wave
// then independently computes its 64 rows: A-frags streamed from abuf
// (L2-resident) with 2-deep prefetch; B-frags via barrier-free ds_read.
// Swizzle: XCD x = bid&7 gets j=bid>>3 in [0,256): ct = j&15 (FAST),
// Grow = x*16 + (j>>4) (SLOW) -> concurrent blocks per XCD share A
// (~1 MB A + 1 MB B working set < 4 MB L2).
__global__ __launch_bounds__(NTHR, 2) void k_score(const short8* __restrict__ abuf,
                                                   const short8* __restrict__ bbuf,
                                                   const float* __restrict__ cbsq,
                                                   u64* __restrict__ keys) {
  __shared__ short8 sB[4096];  // 64 KB: [s(8)][ni(4)][reg(2)][lane(64)]
  const int t = threadIdx.x;
  const int w = t >> 6;
  const int lane = t & 63;
  const int l15 = lane & 15;
  const int quad = lane >> 4;

  const int bid = blockIdx.x;
  const int x = bid & 7;                // XCD (round-robin dispatch)
  const int j = bid >> 3;               // [0,256)
  const int ct = j & 15;                // codeTile FAST: codes ct*64..
  const int Grow = x * 16 + (j >> 4);   // rowGroup SLOW: rows Grow*256..

  // ---- load B tile (half of a 128-code bbuf run) into LDS, once ----
  {
    const short8* gB = bbuf + (size_t)(ct >> 1) * 8192 + (ct & 1) * 512 + t;
    char* lB = (char*)sB + (size_t)(w * 64) * 16;
#pragma unroll
    for (int s = 0; s < 8; ++s) {
#pragma unroll
      for (int i = 0; i < 2; ++i)
        cp16(gB + s * 1024 + i * 256, lB + (s * 512 + i * 256) * 16);
    }
  }
  __syncthreads();   // single full drain; B is read-only hereafter

  f32x4 C[4][4];
#pragma unroll
  for (int mi = 0; mi < 4; ++mi)
#pragma unroll
    for (int ni = 0; ni < 4; ++ni) C[mi][ni] = (f32x4)0.f;

  // wave's 64-row group: g64 = Grow*4 + w
  const int g64 = Grow * 4 + w;
  const short8* gA = abuf + (size_t)(g64 >> 1) * 8192 + (g64 & 1) * 512 + lane;

  short8 ah[3][4], al[3][4];            // 2-deep prefetch ring (static idx)
#pragma unroll
  for (int mi = 0; mi < 4; ++mi) {
    ah[0][mi] = gA[mi * 128];
    al[0][mi] = gA[mi * 128 + 64];
  }
#pragma unroll
  for (int mi = 0; mi < 4; ++mi) {
    ah[1][mi] = gA[1024 + mi * 128];
    al[1][mi] = gA[1024 + mi * 128 + 64];
  }
#pragma unroll
  for (int s = 0; s < 8; ++s) {
    const int cur = s % 3, pf = (s + 2) % 3;
    if (s < 6) {
#pragma unroll
      for (int mi = 0; mi < 4; ++mi) {
        ah[pf][mi] = gA[(s + 2) * 1024 + mi * 128];
        al[pf][mi] = gA[(s + 2) * 1024 + mi * 128 + 64];
      }
    }
#pragma unroll
    for (int ni = 0; ni < 4; ++ni) {
      const short8 bh = sB[s * 512 + ni * 128 + lane];
      const short8 bl = sB[s * 512 + ni * 128 + 64 + lane];
#pragma unroll
      for (int mi = 0; mi < 4; ++mi)
        C[mi][ni] = __builtin_amdgcn_mfma_f32_16x16x32_bf16(ah[cur][mi], bh, C[mi][ni], 0, 0, 0);
#pragma unroll
      for (int mi = 0; mi < 4; ++mi)
        C[mi][ni] = __builtin_amdgcn_mfma_f32_16x16x32_bf16(al[cur][mi], bh, C[mi][ni], 0, 0, 0);
#pragma unroll
      for (int mi = 0; mi < 4; ++mi)
        C[mi][ni] = __builtin_amdgcn_mfma_f32_16x16x32_bf16(ah[cur][mi], bl, C[mi][ni], 0, 0, 0);
    }
  }

  // ---- epilogue: dist = cbsq - 2*dot, per-lane then cross-lane argmin,
  //      then one u64 atomicMin per row ----
  float cs[4];
#pragma unroll
  for (int ni = 0; ni < 4; ++ni) cs[ni] = cbsq[ct * 64 + ni * 16 + l15];

  float best[16];
  int bidx[16];
#pragma unroll
  for (int mi = 0; mi < 4; ++mi)
#pragma unroll
    for (int r = 0; r < 4; ++r) {
      float bd = 3.4e38f;
      int bi = 0;
#pragma unroll
      for (int ni = 0; ni < 4; ++ni) {
        const float d = fmaf(-2.f, C[mi][ni][r], cs[ni]);
        const int code = ct * 64 + ni * 16 + l15;
        if (d < bd) { bd = d; bi = code; }
      }
      best[mi * 4 + r] = bd;
      bidx[mi * 4 + r] = bi;
    }
#pragma unroll
  for (int m = 1; m <= 8; m <<= 1) {
#pragma unroll
    for (int jj = 0; jj < 16; ++jj) {
      const float od = __shfl_xor(best[jj], m, 64);
      const int oi = __shfl_xor(bidx[jj], m, 64);
      if (od < best[jj] || (od == best[jj] && oi < bidx[jj])) { best[jj] = od; bidx[jj] = oi; }
    }
  }
  if (l15 == 0) {
#pragma unroll
    for (int mi = 0; mi < 4; ++mi)
#pragma unroll
      for (int r = 0; r < 4; ++r) {
        const int row = Grow * 256 + w * 64 + mi * 16 + quad * 4 + r;
        const u64 key = ((u64)fenc(best[mi * 4 + r]) << 32) | (unsigned)bidx[mi * 4 + r];
        atomicMin(&keys[row], key);
      }
  }
}

// ---- gather + straight-through out + masked MSE (argmin already merged) ----
__global__ __launch_bounds__(NTHR) void k_gather(const float* __restrict__ feat,
                                                 const float* __restrict__ cb,
                                                 const float* __restrict__ mask,
                                                 const u64* __restrict__ keys,
                                                 float* __restrict__ outq,
                                                 float* __restrict__ lsum) {
  const int t = threadIdx.x;
  const int row0 = blockIdx.x * 64;
  __shared__ int skid[64];
  if (t < 64) skid[t] = (int)(unsigned)(keys[row0 + t] & 0xffffffffu);
  __syncthreads();
  const int wv = t >> 6;
  const int dg = t & 63;
  const int b = row0 >> 11;
  float acc = 0.f;
#pragma unroll
  for (int i = 0; i < 16; ++i) {
    const int r = wv * 16 + i;
    const size_t row = row0 + r;
    const int k = skid[r];
    const float4 q = ((const float4*)cb)[k * (DIM / 4) + dg];
    const float4 x = ((const float4*)feat)[row * (DIM / 4) + dg];
    float4 o;
    o.x = x.x + (q.x - x.x);
    o.y = x.y + (q.y - x.y);
    o.z = x.z + (q.z - x.z);
    o.w = x.w + (q.w - x.w);
    ((float4*)outq)[row * (DIM / 4) + dg] = o;
    const float m = mask[row];
    const float dx = x.x - q.x, dy = x.y - q.y, dz = x.z - q.z, dw = x.w - q.w;
    acc = fmaf(m, dx * dx + dy * dy + dz * dz + dw * dw, acc);
  }
  acc = wave_reduce_sum(acc);
  __shared__ float red[4];
  if ((t & 63) == 0) red[wv] = acc;
  __syncthreads();
  if (t == 0) atomicAdd(&lsum[b], red[0] + red[1] + red[2] + red[3]);
}

__global__ void k_final(const float* __restrict__ lsum,
                        const float* __restrict__ denom,
                        float* __restrict__ outl) {
  const int t = threadIdx.x;
  if (t < BATCH) {
    const float v = lsum[t] / denom[t];
    outl[t] = v;          // quant_loss
    outl[BATCH + t] = v;  // commit_loss (identical in forward)
  }
}

extern "C" void kernel_launch(void* const* d_in, const int* in_sizes, int n_in,
                              void* d_out, int out_size, void* d_ws, size_t ws_size,
                              hipStream_t stream) {
  const float* feat = (const float*)d_in[0];  // [16,2048,256]
  const float* mask = (const float*)d_in[1];  // [16,2048]
  const float* cb   = (const float*)d_in[2];  // [1024,256]
  float* out = (float*)d_out;

  char* p = (char*)d_ws;
  short8* abuf = (short8*)p;                 p += (size_t)2048 * 1024 * 16;  // 33.55 MB
  short8* bbuf = (short8*)p;                 p += (size_t)64 * 1024 * 16;    // 1.05 MB
  float* cbsq  = (float*)p;                  p += NCODES * 4;
  u64*   keys  = (u64*)p;                    p += (size_t)NROWS * 8;         // 256 KB
  float* denom = (float*)p;                  p += BATCH * 4;
  float* lsum  = (float*)p;

  k_prep<<<2048 + 64 + 16 + 16, NTHR, 0, stream>>>(feat, cb, mask, abuf, bbuf, cbsq, denom, lsum, keys);
  k_score<<<2048, NTHR, 0, stream>>>(abuf, bbuf, cbsq, keys);
  k_gather<<<NROWS / 64, NTHR, 0, stream>>>(feat, cb, mask, keys, out, lsum);
  k_final<<<1, 64, 0, stream>>>(lsum, denom, out + (size_t)NROWS * DIM);
}

// Round 5
// 170.455 us; speedup vs baseline: 1.1315x; 1.1315x over previous
//
#include <hip/hip_runtime.h>

#define DIM    256
#define NCODES 1024
#define BATCH  16
#define SEQ    2048
#define NROWS  (BATCH * SEQ)   // 32768
#define NTHR   256
#define NGRP   16              // 16 ng tiles of 64 codes

typedef short short8 __attribute__((ext_vector_type(8)));
typedef float f32x4 __attribute__((ext_vector_type(4)));

__device__ __forceinline__ float wave_reduce_sum(float s) {
#pragma unroll
  for (int off = 32; off > 0; off >>= 1) s += __shfl_down(s, off, 64);
  return s;
}

// round-to-nearest-even float -> bf16 (raw short)
__device__ __forceinline__ short f2bf(float f) {
  unsigned u = __builtin_bit_cast(unsigned, f);
  u = (u + 0x7fff + ((u >> 16) & 1)) >> 16;
  return (short)u;
}
__device__ __forceinline__ float bf2f(short s) {
  unsigned u = ((unsigned)(unsigned short)s) << 16;
  return __builtin_bit_cast(float, u);
}

// async global -> LDS, 16B per lane. LDS dest = wave-uniform base + lane*16.
__device__ __forceinline__ void cp16(const void* g, void* l) {
  __builtin_amdgcn_global_load_lds(
      (const __attribute__((address_space(1))) unsigned*)g,
      (__attribute__((address_space(3))) unsigned*)l, 16, 0, 0);
}

// ---- fused prep: A-plane split (blocks 0..2047), B pack (2048..2111),
//      mask/denom (2112..2127) ----
// abuf: [(R*8+s)*1024 + ((rb16*2+reg)*4+kgl)*16 + m] short8
//   row = R*128 + rb16*16 + m ; dims = s*32 + kgl*8 + j ; reg0=hi reg1=lo
// bbuf: [(g128*8+s)*1024 + ((nb8*2+reg)*4+kgl)*16 + m] short8
//   code = g128*128 + nb8*16 + m ; dims = s*32 + kgl*8 + j
__global__ __launch_bounds__(NTHR) void k_prep(const float* __restrict__ feat,
                                               const float* __restrict__ cb,
                                               const float* __restrict__ mask,
                                               short8* __restrict__ abuf,
                                               short8* __restrict__ bbuf,
                                               float* __restrict__ cbsq,
                                               float* __restrict__ denom,
                                               float* __restrict__ lsum) {
  const int bid = blockIdx.x;
  const int t = threadIdx.x;
  __shared__ float tile[16 * 257];
  if (bid < 2048) {
    // ---- prep A: one (rowTile R, chunk s) per block ----
    const int R = bid >> 3;
    const int s = bid & 7;
    const float4* __restrict__ fsrc = (const float4*)feat;
    short8* dst = abuf + (size_t)(R * 8 + s) * 1024;
#pragma unroll
    for (int it = 0; it < 2; ++it) {
      const int p = it * NTHR + t;       // 512 items
      const int rl = p >> 2;             // row_local [0,128)
      const int kgl = p & 3;
      const int row = R * 128 + rl;
      const size_t f4 = (size_t)row * 64 + s * 8 + kgl * 2;
      const float4 x0 = fsrc[f4];
      const float4 x1 = fsrc[f4 + 1];
      const float xs[8] = {x0.x, x0.y, x0.z, x0.w, x1.x, x1.y, x1.z, x1.w};
      short8 hi, lo;
#pragma unroll
      for (int j = 0; j < 8; ++j) {
        const short hh = f2bf(xs[j]);
        hi[j] = hh;
        lo[j] = f2bf(xs[j] - bf2f(hh));
      }
      const int rb16 = rl >> 4, m = rl & 15;
      dst[((rb16 * 2 + 0) * 4 + kgl) * 16 + m] = hi;
      dst[((rb16 * 2 + 1) * 4 + kgl) * 16 + m] = lo;
    }
  } else if (bid < 2112) {
    // ---- prep B: 16 codes per block ----
    const int nb = bid - 2048;
    const float* src = cb + (size_t)nb * 16 * DIM;
#pragma unroll
    for (int i = 0; i < 16; ++i) tile[i * 257 + t] = src[i * DIM + t];
    __syncthreads();
#pragma unroll
    for (int it = 0; it < 4; ++it) {
      const int idx = it * NTHR + t;
      const int kg = idx >> 4;
      const int m = idx & 15;
      const int reg = kg >> 5;
      const int sk = kg & 31;
      const int sg = sk >> 2;
      const int kgl = sk & 3;
      short8 v;
#pragma unroll
      for (int j = 0; j < 8; ++j) {
        const float w = tile[m * 257 + sk * 8 + j];
        const short h = f2bf(w);
        v[j] = reg ? f2bf(w - bf2f(h)) : h;
      }
      bbuf[(size_t)((nb >> 3) * 8 + sg) * 1024 +
           (((nb & 7) * 2 + reg) * 4 + kgl) * 16 + m] = v;
    }
    if (t < 16) {
      float s2 = 0.f;
      for (int c = 0; c < DIM; ++c) { const float w = tile[t * 257 + c]; s2 = fmaf(w, w, s2); }
      cbsq[nb * 16 + t] = s2;
    }
  } else {
    // ---- mask sums + zero loss accumulators ----
    const int b = bid - 2112;
    float s = 0.f;
    for (int i = t; i < SEQ; i += NTHR) s += mask[b * SEQ + i];
    s = wave_reduce_sum(s);
    __shared__ float red[NTHR / 64];
    if ((t & 63) == 0) red[t >> 6] = s;
    __syncthreads();
    if (t == 0) { denom[b] = red[0] + red[1] + red[2] + red[3]; lsum[b] = 0.f; }
  }
}

// ---- MFMA score + partial argmin; 2-phase pipeline with counted vmcnt ----
// Block tile: 128 rows x 128 codes. Round-1 skeleton (proved FETCH=20.6MB,
// 0 conflicts) + T3-minimal pipeline: per chunk {STAGE next buf -> COMPUTE
// current -> asm vmcnt(0) -> raw s_barrier}. The vmcnt(0) lands after ~931
// cycles of MFMA have covered the load latency; __syncthreads (which would
// force the drain BEFORE compute) is never used in the loop.
__global__ __launch_bounds__(NTHR, 2) void k_score(const short8* __restrict__ abuf,
                                                   const short8* __restrict__ bbuf,
                                                   const float* __restrict__ cbsq,
                                                   float* __restrict__ pdist,
                                                   int* __restrict__ pidx) {
  __shared__ short8 sA0[1024];  // 16 KB each, 64 KB total -> 2 blocks/CU
  __shared__ short8 sB0[1024];  // distinct arrays: alias analysis keeps
  __shared__ short8 sA1[1024];  // prefetch (vm) independent of ds_read (lgkm)
  __shared__ short8 sB1[1024];
  const int t = threadIdx.x;
  const int w = t >> 6;
  const int lane = t & 63;
  const int l15 = lane & 15;
  const int quad = lane >> 4;
  // bijective XCD swizzle (round-1 proven): XCD x gets 32 contiguous rowTiles
  const int bid = blockIdx.x;
  const int wgid = (bid & 7) * 256 + (bid >> 3);
  const int R = wgid >> 3;          // rowTile [0,256)
  const int Ncd = wgid & 7;         // codeTile [0,8)
  const int h = w >> 1;             // row half
  const int c = w & 1;              // code half

  f32x4 C[4][4];
#pragma unroll
  for (int mi = 0; mi < 4; ++mi)
#pragma unroll
    for (int ni = 0; ni < 4; ++ni) C[mi][ni] = (f32x4)0.f;

  const short8* gA = abuf + (size_t)R * 8192 + t;    // per-lane src, linear
  const short8* gB = bbuf + (size_t)Ncd * 8192 + t;

  auto stage = [&](short8* dA, short8* dB, int s) {
    char* lA = (char*)dA + (size_t)(w * 64) * 16;    // wave-uniform dest
    char* lB = (char*)dB + (size_t)(w * 64) * 16;
#pragma unroll
    for (int i = 0; i < 4; ++i) {
      cp16(gA + s * 1024 + i * 256, lA + i * 4096);
      cp16(gB + s * 1024 + i * 256, lB + i * 4096);
    }
  };

  auto compute = [&](const short8* cA, const short8* cB) {
    short8 ah[4], al[4], bh[4], bl[4];
#pragma unroll
    for (int mi = 0; mi < 4; ++mi) {
      ah[mi] = cA[(h * 4 + mi) * 128 + lane];
      al[mi] = cA[(h * 4 + mi) * 128 + 64 + lane];
    }
#pragma unroll
    for (int ni = 0; ni < 4; ++ni) {
      bh[ni] = cB[(c * 4 + ni) * 128 + lane];
      bl[ni] = cB[(c * 4 + ni) * 128 + 64 + lane];
    }
#pragma unroll
    for (int mi = 0; mi < 4; ++mi)
#pragma unroll
      for (int ni = 0; ni < 4; ++ni)
        C[mi][ni] = __builtin_amdgcn_mfma_f32_16x16x32_bf16(ah[mi], bh[ni], C[mi][ni], 0, 0, 0);
#pragma unroll
    for (int mi = 0; mi < 4; ++mi)
#pragma unroll
      for (int ni = 0; ni < 4; ++ni)
        C[mi][ni] = __builtin_amdgcn_mfma_f32_16x16x32_bf16(al[mi], bh[ni], C[mi][ni], 0, 0, 0);
#pragma unroll
    for (int mi = 0; mi < 4; ++mi)
#pragma unroll
      for (int ni = 0; ni < 4; ++ni)
        C[mi][ni] = __builtin_amdgcn_mfma_f32_16x16x32_bf16(ah[mi], bl[ni], C[mi][ni], 0, 0, 0);
  };

  stage(sA0, sB0, 0);
  asm volatile("s_waitcnt vmcnt(0)" ::: "memory");
  __builtin_amdgcn_s_barrier();
#pragma unroll
  for (int s = 0; s < 8; ++s) {
    const short8* cA = (s & 1) ? (const short8*)sA1 : (const short8*)sA0;
    const short8* cB = (s & 1) ? (const short8*)sB1 : (const short8*)sB0;
    short8* nA = (s & 1) ? sA0 : sA1;
    short8* nB = (s & 1) ? sB0 : sB1;
    if (s < 7) stage(nA, nB, s + 1);   // issue next-chunk loads FIRST
    compute(cA, cB);                   // ~931 cyc of MFMA covers their latency
    if (s < 7) {
      asm volatile("s_waitcnt vmcnt(0)" ::: "memory");  // cheap: latency covered
      __builtin_amdgcn_s_barrier();    // next buf ready; my reads already in regs
    }
  }

  // ---- epilogue: dist = cbsq - 2*dot, per-lane then cross-lane argmin ----
  float cs[4];
#pragma unroll
  for (int ni = 0; ni < 4; ++ni) cs[ni] = cbsq[Ncd * 128 + c * 64 + ni * 16 + l15];

  float best[16];
  int bidx[16];
#pragma unroll
  for (int mi = 0; mi < 4; ++mi)
#pragma unroll
    for (int r = 0; r < 4; ++r) {
      float bd = 3.4e38f;
      int bi = 0;
#pragma unroll
      for (int ni = 0; ni < 4; ++ni) {
        const float d = fmaf(-2.f, C[mi][ni][r], cs[ni]);
        const int code = Ncd * 128 + c * 64 + ni * 16 + l15;
        if (d < bd) { bd = d; bi = code; }
      }
      best[mi * 4 + r] = bd;
      bidx[mi * 4 + r] = bi;
    }
#pragma unroll
  for (int m = 1; m <= 8; m <<= 1) {
#pragma unroll
    for (int j = 0; j < 16; ++j) {
      const float od = __shfl_xor(best[j], m, 64);
      const int oi = __shfl_xor(bidx[j], m, 64);
      if (od < best[j] || (od == best[j] && oi < bidx[j])) { best[j] = od; bidx[j] = oi; }
    }
  }
  if (l15 == 0) {
    const int ng = Ncd * 2 + c;
#pragma unroll
    for (int mi = 0; mi < 4; ++mi)
#pragma unroll
      for (int r = 0; r < 4; ++r) {
        const int row = R * 128 + h * 64 + mi * 16 + quad * 4 + r;
        pdist[row * NGRP + ng] = best[mi * 4 + r];
        pidx[row * NGRP + ng] = bidx[mi * 4 + r];
      }
  }
}

// ---- fused merge + gather + straight-through out + masked MSE ----
__global__ __launch_bounds__(NTHR) void k_gather(const float* __restrict__ feat,
                                                 const float* __restrict__ cb,
                                                 const float* __restrict__ mask,
                                                 const float* __restrict__ pdist,
                                                 const int* __restrict__ pidx,
                                                 float* __restrict__ outq,
                                                 float* __restrict__ lsum) {
  const int t = threadIdx.x;
  const int row0 = blockIdx.x * 64;
  __shared__ float sd[NTHR];
  __shared__ int si[NTHR];
  __shared__ int skid[64];
  {
    const float4 pd = ((const float4*)pdist)[row0 * 4 + t];
    const int4 pi = ((const int4*)pidx)[row0 * 4 + t];
    float bd = pd.x; int bi = pi.x;
    if (pd.y < bd || (pd.y == bd && pi.y < bi)) { bd = pd.y; bi = pi.y; }
    if (pd.z < bd || (pd.z == bd && pi.z < bi)) { bd = pd.z; bi = pi.z; }
    if (pd.w < bd || (pd.w == bd && pi.w < bi)) { bd = pd.w; bi = pi.w; }
    sd[t] = bd; si[t] = bi;
  }
  __syncthreads();
  if (t < 64) {
    float bd = sd[t * 4]; int bi = si[t * 4];
#pragma unroll
    for (int j = 1; j < 4; ++j) {
      const float od = sd[t * 4 + j]; const int oi = si[t * 4 + j];
      if (od < bd || (od == bd && oi < bi)) { bd = od; bi = oi; }
    }
    skid[t] = bi;
  }
  __syncthreads();
  const int wv = t >> 6;
  const int dg = t & 63;
  const int b = row0 >> 11;
  float acc = 0.f;
#pragma unroll
  for (int i = 0; i < 16; ++i) {
    const int r = wv * 16 + i;
    const size_t row = row0 + r;
    const int k = skid[r];
    const float4 q = ((const float4*)cb)[k * (DIM / 4) + dg];
    const float4 x = ((const float4*)feat)[row * (DIM / 4) + dg];
    float4 o;
    o.x = x.x + (q.x - x.x);
    o.y = x.y + (q.y - x.y);
    o.z = x.z + (q.z - x.z);
    o.w = x.w + (q.w - x.w);
    ((float4*)outq)[row * (DIM / 4) + dg] = o;
    const float m = mask[row];
    const float dx = x.x - q.x, dy = x.y - q.y, dz = x.z - q.z, dw = x.w - q.w;
    acc = fmaf(m, dx * dx + dy * dy + dz * dz + dw * dw, acc);
  }
  acc = wave_reduce_sum(acc);
  __shared__ float red[4];
  if ((t & 63) == 0) red[wv] = acc;
  __syncthreads();
  if (t == 0) atomicAdd(&lsum[b], red[0] + red[1] + red[2] + red[3]);
}

__global__ void k_final(const float* __restrict__ lsum,
                        const float* __restrict__ denom,
                        float* __restrict__ outl) {
  const int t = threadIdx.x;
  if (t < BATCH) {
    const float v = lsum[t] / denom[t];
    outl[t] = v;          // quant_loss
    outl[BATCH + t] = v;  // commit_loss (identical in forward)
  }
}

extern "C" void kernel_launch(void* const* d_in, const int* in_sizes, int n_in,
                              void* d_out, int out_size, void* d_ws, size_t ws_size,
                              hipStream_t stream) {
  const float* feat = (const float*)d_in[0];  // [16,2048,256]
  const float* mask = (const float*)d_in[1];  // [16,2048]
  const float* cb   = (const float*)d_in[2];  // [1024,256]
  float* out = (float*)d_out;

  char* p = (char*)d_ws;
  short8* abuf = (short8*)p;                 p += (size_t)2048 * 1024 * 16;  // 33.55 MB
  short8* bbuf = (short8*)p;                 p += (size_t)64 * 1024 * 16;    // 1.05 MB
  float* cbsq  = (float*)p;                  p += NCODES * 4;
  float* pdist = (float*)p;                  p += (size_t)NROWS * NGRP * 4;  // 2 MB
  int*   pidx  = (int*)p;                    p += (size_t)NROWS * NGRP * 4;  // 2 MB
  float* denom = (float*)p;                  p += BATCH * 4;
  float* lsum  = (float*)p;

  k_prep<<<2048 + 64 + 16, NTHR, 0, stream>>>(feat, cb, mask, abuf, bbuf, cbsq, denom, lsum);
  k_score<<<2048, NTHR, 0, stream>>>(abuf, bbuf, cbsq, pdist, pidx);
  k_gather<<<NROWS / 64, NTHR, 0, stream>>>(feat, cb, mask, pdist, pidx, out, lsum);
  k_final<<<1, 64, 0, stream>>>(lsum, denom, out + (size_t)NROWS * DIM);
}

// Round 7
// 162.329 us; speedup vs baseline: 1.1881x; 1.0501x over previous
//
#include <hip/hip_runtime.h>

#define DIM    256
#define NCODES 1024
#define BATCH  16
#define SEQ    2048
#define NROWS  (BATCH * SEQ)   // 32768
#define NTHR   256

typedef short short8 __attribute__((ext_vector_type(8)));
typedef float f32x4 __attribute__((ext_vector_type(4)));

__device__ __forceinline__ float wave_reduce_sum(float s) {
#pragma unroll
  for (int off = 32; off > 0; off >>= 1) s += __shfl_down(s, off, 64);
  return s;
}

// round-to-nearest-even float -> bf16 (raw short)
__device__ __forceinline__ short f2bf(float f) {
  unsigned u = __builtin_bit_cast(unsigned, f);
  u = (u + 0x7fff + ((u >> 16) & 1)) >> 16;
  return (short)u;
}
__device__ __forceinline__ float bf2f(short s) {
  unsigned u = ((unsigned)(unsigned short)s) << 16;
  return __builtin_bit_cast(float, u);
}

// async global -> LDS, 16B per lane. LDS dest = wave-uniform base + lane*16.
__device__ __forceinline__ void cp16(const void* g, void* l) {
  __builtin_amdgcn_global_load_lds(
      (const __attribute__((address_space(1))) unsigned*)g,
      (__attribute__((address_space(3))) unsigned*)l, 16, 0, 0);
}

// ---- fused prep: A-plane split (blocks 0..2047), B pack (2048..2111),
//      mask/denom (2112..2127) ----
// abuf: [(R*8+s)*1024 + ((rb16*2+reg)*4+kgl)*16 + m] short8
//   row = R*128 + rb16*16 + m ; dims = s*32 + kgl*8 + j ; reg0=hi reg1=lo
// bbuf: [(g128*8+s)*1024 + ((nb8*2+reg)*4+kgl)*16 + m] short8
//   code = g128*128 + nb8*16 + m ; dims = s*32 + kgl*8 + j
__global__ __launch_bounds__(NTHR) void k_prep(const float* __restrict__ feat,
                                               const float* __restrict__ cb,
                                               const float* __restrict__ mask,
                                               short8* __restrict__ abuf,
                                               short8* __restrict__ bbuf,
                                               float* __restrict__ cbsq,
                                               float* __restrict__ denom,
                                               float* __restrict__ lsum) {
  const int bid = blockIdx.x;
  const int t = threadIdx.x;
  __shared__ float tile[16 * 257];
  if (bid < 2048) {
    // ---- prep A: one (rowTile R, chunk s) per block ----
    const int R = bid >> 3;
    const int s = bid & 7;
    const float4* __restrict__ fsrc = (const float4*)feat;
    short8* dst = abuf + (size_t)(R * 8 + s) * 1024;
#pragma unroll
    for (int it = 0; it < 2; ++it) {
      const int p = it * NTHR + t;       // 512 items
      const int rl = p >> 2;             // row_local [0,128)
      const int kgl = p & 3;
      const int row = R * 128 + rl;
      const size_t f4 = (size_t)row * 64 + s * 8 + kgl * 2;
      const float4 x0 = fsrc[f4];
      const float4 x1 = fsrc[f4 + 1];
      const float xs[8] = {x0.x, x0.y, x0.z, x0.w, x1.x, x1.y, x1.z, x1.w};
      short8 hi, lo;
#pragma unroll
      for (int j = 0; j < 8; ++j) {
        const short hh = f2bf(xs[j]);
        hi[j] = hh;
        lo[j] = f2bf(xs[j] - bf2f(hh));
      }
      const int rb16 = rl >> 4, m = rl & 15;
      dst[((rb16 * 2 + 0) * 4 + kgl) * 16 + m] = hi;
      dst[((rb16 * 2 + 1) * 4 + kgl) * 16 + m] = lo;
    }
  } else if (bid < 2112) {
    // ---- prep B: 16 codes per block ----
    const int nb = bid - 2048;
    const float* src = cb + (size_t)nb * 16 * DIM;
#pragma unroll
    for (int i = 0; i < 16; ++i) tile[i * 257 + t] = src[i * DIM + t];
    __syncthreads();
#pragma unroll
    for (int it = 0; it < 4; ++it) {
      const int idx = it * NTHR + t;
      const int kg = idx >> 4;
      const int m = idx & 15;
      const int reg = kg >> 5;
      const int sk = kg & 31;
      const int sg = sk >> 2;
      const int kgl = sk & 3;
      short8 v;
#pragma unroll
      for (int j = 0; j < 8; ++j) {
        const float w = tile[m * 257 + sk * 8 + j];
        const short h = f2bf(w);
        v[j] = reg ? f2bf(w - bf2f(h)) : h;
      }
      bbuf[(size_t)((nb >> 3) * 8 + sg) * 1024 +
           (((nb & 7) * 2 + reg) * 4 + kgl) * 16 + m] = v;
    }
    if (t < 16) {
      float s2 = 0.f;
      for (int c = 0; c < DIM; ++c) { const float w = tile[t * 257 + c]; s2 = fmaf(w, w, s2); }
      cbsq[nb * 16 + t] = s2;
    }
  } else {
    // ---- mask sums + zero loss accumulators ----
    const int b = bid - 2112;
    float s = 0.f;
    for (int i = t; i < SEQ; i += NTHR) s += mask[b * SEQ + i];
    s = wave_reduce_sum(s);
    __shared__ float red[NTHR / 64];
    if ((t & 63) == 0) red[t >> 6] = s;
    __syncthreads();
    if (t == 0) { denom[b] = red[0] + red[1] + red[2] + red[3]; lsum[b] = 0.f; }
  }
}

// ---- mega kernel: score vs ALL 1024 codes + block-local argmin +
//      gather + straight-through + masked MSE, one block per 64 rows ----
// LDS: sA = 64 rows full-K hi/lo (64 KB, staged once via cp16);
//      sB = one (cg, s) B-chunk (16 KB, round-1 serial stage pattern).
// Total 80 KB -> 2 blocks/CU. No pdist/pidx, no second feat pass kernel.
// Wave tiling: each wave covers all 64 rows (mi=4) x 32 codes (ni=2) of the
// current 128-code group; 4 waves cover the group. MFMA chain per C element
// is hh,lh,hl per chunk with s ascending == previous rounds -> bit-exact.
__global__ __launch_bounds__(NTHR, 2) void k_mega(const short8* __restrict__ abuf,
                                                  const short8* __restrict__ bbuf,
                                                  const float* __restrict__ cbsq,
                                                  const float* __restrict__ feat,
                                                  const float* __restrict__ cb,
                                                  const float* __restrict__ mask,
                                                  float* __restrict__ outq,
                                                  float* __restrict__ lsum) {
  __shared__ short8 sA[4096];  // 64 KB: slot = ((s*4+mi)*2+reg)*64 + kgl*16 + m
  __shared__ short8 sB[1024];  // 16 KB: one chunk; overlaid by merge scratch later
  const int t = threadIdx.x;
  const int w = t >> 6;
  const int lane = t & 63;
  const int l15 = lane & 15;
  const int quad = lane >> 4;
  const int blk = blockIdx.x;        // 512 blocks x 64 rows
  const int row0 = blk * 64;
  const int Rt = blk >> 1;           // 128-row abuf tile
  const int h = blk & 1;             // which 64-row half of the tile

  // ---- stage A once: 4096 slots, 16 cp16 rounds, linear LDS dest ----
#pragma unroll
  for (int i = 0; i < 16; ++i) {
    const int slot = i * NTHR + t;
    const int s = slot >> 9;
    const int mi = (slot >> 7) & 3;
    const int reg = (slot >> 6) & 1;
    const int low = slot & 63;       // kgl*16 + m
    cp16(abuf + (size_t)Rt * 8192 + s * 1024 + ((h * 4 + mi) * 2 + reg) * 64 + low,
         (char*)sA + (size_t)(i * NTHR + w * 64) * 16);
  }

  float best[16];
  int bidx[16];
#pragma unroll
  for (int j = 0; j < 16; ++j) { best[j] = 3.4e38f; bidx[j] = 0; }

#pragma unroll 1
  for (int cg = 0; cg < 8; ++cg) {   // 128-code groups
    f32x4 C[4][2];
#pragma unroll
    for (int mi = 0; mi < 4; ++mi)
#pragma unroll
      for (int ni = 0; ni < 2; ++ni) C[mi][ni] = (f32x4)0.f;

#pragma unroll
    for (int s = 0; s < 8; ++s) {
      __syncthreads();               // prev chunk's readers done
      {
        const short8* gB = bbuf + ((size_t)cg * 8 + s) * 1024 + t;
        char* lB = (char*)sB + (size_t)(w * 64) * 16;
#pragma unroll
        for (int i = 0; i < 4; ++i) cp16(gB + i * 256, lB + i * 4096);
      }
      __syncthreads();               // drain (covers A-stage on first pass)
      short8 ah[4], al[4], bh[2], bl[2];
#pragma unroll
      for (int mi = 0; mi < 4; ++mi) {
        ah[mi] = sA[((s * 4 + mi) * 2 + 0) * 64 + quad * 16 + l15];
        al[mi] = sA[((s * 4 + mi) * 2 + 1) * 64 + quad * 16 + l15];
      }
#pragma unroll
      for (int ni = 0; ni < 2; ++ni) {
        bh[ni] = sB[((w * 2 + ni) * 2 + 0) * 64 + quad * 16 + l15];
        bl[ni] = sB[((w * 2 + ni) * 2 + 1) * 64 + quad * 16 + l15];
      }
#pragma unroll
      for (int mi = 0; mi < 4; ++mi)
#pragma unroll
        for (int ni = 0; ni < 2; ++ni)
          C[mi][ni] = __builtin_amdgcn_mfma_f32_16x16x32_bf16(ah[mi], bh[ni], C[mi][ni], 0, 0, 0);
#pragma unroll
      for (int mi = 0; mi < 4; ++mi)
#pragma unroll
        for (int ni = 0; ni < 2; ++ni)
          C[mi][ni] = __builtin_amdgcn_mfma_f32_16x16x32_bf16(al[mi], bh[ni], C[mi][ni], 0, 0, 0);
#pragma unroll
      for (int mi = 0; mi < 4; ++mi)
#pragma unroll
        for (int ni = 0; ni < 2; ++ni)
          C[mi][ni] = __builtin_amdgcn_mfma_f32_16x16x32_bf16(ah[mi], bl[ni], C[mi][ni], 0, 0, 0);
    }

    // ---- fold this code-group into per-lane running argmin ----
    float cs[2];
#pragma unroll
    for (int ni = 0; ni < 2; ++ni) cs[ni] = cbsq[cg * 128 + w * 32 + ni * 16 + l15];
#pragma unroll
    for (int mi = 0; mi < 4; ++mi)
#pragma unroll
      for (int r = 0; r < 4; ++r) {
        const int j = mi * 4 + r;
#pragma unroll
        for (int ni = 0; ni < 2; ++ni) {
          const float d = fmaf(-2.f, C[mi][ni][r], cs[ni]);
          const int code = cg * 128 + w * 32 + ni * 16 + l15;
          if (d < best[j]) { best[j] = d; bidx[j] = code; }  // codes ascending
        }
      }
  }

  // ---- cross-lane argmin (over the 16 l15 code-columns) ----
#pragma unroll
  for (int m = 1; m <= 8; m <<= 1) {
#pragma unroll
    for (int j = 0; j < 16; ++j) {
      const float od = __shfl_xor(best[j], m, 64);
      const int oi = __shfl_xor(bidx[j], m, 64);
      if (od < best[j] || (od == best[j] && oi < bidx[j])) { best[j] = od; bidx[j] = oi; }
    }
  }

  // ---- cross-wave merge via LDS (overlay sB; all sB reads are done) ----
  float* md = (float*)sB;                      // [4][64]
  int* mim = (int*)((char*)sB + 1024);         // [4][64]
  int* skid = (int*)((char*)sB + 2048);        // [64]
  float* red = (float*)((char*)sB + 2304);     // [4]
  __syncthreads();                             // everyone done reading sB
  if (l15 == 0) {
#pragma unroll
    for (int mi = 0; mi < 4; ++mi)
#pragma unroll
      for (int r = 0; r < 4; ++r) {
        const int row = mi * 16 + quad * 4 + r;
        md[w * 64 + row] = best[mi * 4 + r];
        mim[w * 64 + row] = bidx[mi * 4 + r];
      }
  }
  __syncthreads();
  if (t < 64) {
    float bd = md[t];
    int bi = mim[t];
#pragma unroll
    for (int ww = 1; ww < 4; ++ww) {
      const float od = md[ww * 64 + t];
      const int oi = mim[ww * 64 + t];
      if (od < bd || (od == bd && oi < bi)) { bd = od; bi = oi; }
    }
    skid[t] = bi;
  }
  __syncthreads();

  // ---- epilogue: gather + straight-through out + masked MSE ----
  const int wv = w;
  const int dg = lane;
  const int b = row0 >> 11;
  float acc = 0.f;
#pragma unroll
  for (int i = 0; i < 16; ++i) {
    const int r = wv * 16 + i;
    const size_t row = row0 + r;
    const int k = skid[r];
    const float4 q = ((const float4*)cb)[k * (DIM / 4) + dg];
    const float4 x = ((const float4*)feat)[row * (DIM / 4) + dg];
    float4 o;
    o.x = x.x + (q.x - x.x);
    o.y = x.y + (q.y - x.y);
    o.z = x.z + (q.z - x.z);
    o.w = x.w + (q.w - x.w);
    ((float4*)outq)[row * (DIM / 4) + dg] = o;
    const float m = mask[row];
    const float dx = x.x - q.x, dy = x.y - q.y, dz = x.z - q.z, dw = x.w - q.w;
    acc = fmaf(m, dx * dx + dy * dy + dz * dz + dw * dw, acc);
  }
  acc = wave_reduce_sum(acc);
  if (lane == 0) red[wv] = acc;
  __syncthreads();
  if (t == 0) atomicAdd(&lsum[b], red[0] + red[1] + red[2] + red[3]);
}

__global__ void k_final(const float* __restrict__ lsum,
                        const float* __restrict__ denom,
                        float* __restrict__ outl) {
  const int t = threadIdx.x;
  if (t < BATCH) {
    const float v = lsum[t] / denom[t];
    outl[t] = v;          // quant_loss
    outl[BATCH + t] = v;  // commit_loss (identical in forward)
  }
}

extern "C" void kernel_launch(void* const* d_in, const int* in_sizes, int n_in,
                              void* d_out, int out_size, void* d_ws, size_t ws_size,
                              hipStream_t stream) {
  const float* feat = (const float*)d_in[0];  // [16,2048,256]
  const float* mask = (const float*)d_in[1];  // [16,2048]
  const float* cb   = (const float*)d_in[2];  // [1024,256]
  float* out = (float*)d_out;

  char* p = (char*)d_ws;
  short8* abuf = (short8*)p;                 p += (size_t)2048 * 1024 * 16;  // 33.55 MB
  short8* bbuf = (short8*)p;                 p += (size_t)64 * 1024 * 16;    // 1.05 MB
  float* cbsq  = (float*)p;                  p += NCODES * 4;
  float* denom = (float*)p;                  p += BATCH * 4;
  float* lsum  = (float*)p;

  k_prep<<<2048 + 64 + 16, NTHR, 0, stream>>>(feat, cb, mask, abuf, bbuf, cbsq, denom, lsum);
  k_mega<<<NROWS / 64, NTHR, 0, stream>>>(abuf, bbuf, cbsq, feat, cb, mask, out, lsum);
  k_final<<<1, 64, 0, stream>>>(lsum, denom, out + (size_t)NROWS * DIM);
}